// Round 1
// baseline (249.628 us; speedup 1.0000x reference)
//
#include <hip/hip_runtime.h>
#include <hip/hip_bf16.h>
#include <stdint.h>

#define NROWS 8192
#define DDIM  1024
#define NQ    30
#define MARGINF 2.0f

typedef __attribute__((ext_vector_type(8))) short bf16x8;   // 8 bf16 (4 VGPRs)
typedef __attribute__((ext_vector_type(4))) float f32x4;    // MFMA accum

static __device__ __forceinline__ unsigned short f2bf(float f) {
  union { float f; unsigned u; } c; c.f = f;
  return (unsigned short)((c.u + 0x7fffu + ((c.u >> 16) & 1u)) >> 16);  // RNE
}

static __device__ __forceinline__ void gload_lds16(const void* g, void* l) {
  __builtin_amdgcn_global_load_lds(
      (const __attribute__((address_space(1))) void*)g,
      (__attribute__((address_space(3))) void*)l, 16, 0, 0);
}

// ---------------- prep: bf16 cast + row norms + pos term + rowMin init -------
__global__ __launch_bounds__(256) void prep_kernel(
    const float* __restrict__ o1, const float* __restrict__ o2,
    unsigned short* __restrict__ o1b, unsigned short* __restrict__ o2b,
    float* __restrict__ a2, float* __restrict__ b2, float* __restrict__ posr,
    unsigned int* __restrict__ rowMin, int* __restrict__ flag)
{
  const int row = blockIdx.x;
  const int t = threadIdx.x;
  const float4* p1 = (const float4*)(o1 + (size_t)row * DDIM);
  const float4* p2 = (const float4*)(o2 + (size_t)row * DDIM);
  float4 x1 = p1[t];
  float4 x2 = p2[t];
  float s1, s2, sp;
  {
    float a0 = x1.x, a1 = x1.y, aa2 = x1.z, a3 = x1.w;
    float b0 = x2.x, b1 = x2.y, bb2 = x2.z, b3 = x2.w;
    s1 = a0*a0 + a1*a1 + aa2*aa2 + a3*a3;
    s2 = b0*b0 + b1*b1 + bb2*bb2 + b3*b3;
    float d0 = b0-a0, d1 = b1-a1, d2 = bb2-aa2, d3 = b3-a3;
    sp = d0*d0 + d1*d1 + d2*d2 + d3*d3;
    ushort4 v1 = make_ushort4(f2bf(a0), f2bf(a1), f2bf(aa2), f2bf(a3));
    ushort4 v2 = make_ushort4(f2bf(b0), f2bf(b1), f2bf(bb2), f2bf(b3));
    *(ushort4*)(o1b + (size_t)row * DDIM + t * 4) = v1;
    *(ushort4*)(o2b + (size_t)row * DDIM + t * 4) = v2;
  }
  for (int s = 1; s < 64; s <<= 1) {
    s1 += __shfl_xor(s1, s);
    s2 += __shfl_xor(s2, s);
    sp += __shfl_xor(sp, s);
  }
  __shared__ float r1[4], r2[4], rp[4];
  const int wv = t >> 6;
  if ((t & 63) == 0) { r1[wv] = s1; r2[wv] = s2; rp[wv] = sp; }
  __syncthreads();
  if (t == 0) {
    a2[row]   = r1[0] + r1[1] + r1[2] + r1[3];
    b2[row]   = r2[0] + r2[1] + r2[2] + r2[3];
    posr[row] = rp[0] + rp[1] + rp[2] + rp[3];
    rowMin[row] = 0x7F800000u;           // +inf bits
    if (row == 0) *flag = 0;
  }
}

// ---------------- GEMM: gram -> sq; STORE_SQ=0 computes per-row min only ----
// 128x128 tile, BK=32, 4 waves (2x2), 16x16x32 bf16 MFMA, m97-style 2-barrier.
template<int STORE_SQ>
__global__ __launch_bounds__(256) void gemm_kernel(
    const unsigned short* __restrict__ A, const unsigned short* __restrict__ B,
    const float* __restrict__ a2, const float* __restrict__ b2,
    unsigned int* __restrict__ rowMin, const int* __restrict__ flag,
    float* __restrict__ sqbuf, int jBase, int chunkCols)
{
  if (STORE_SQ) { if (*flag == 0) return; }   // fallback path gate (never taken on benign data)
  __shared__ __align__(16) unsigned short lA[128 * 32];   // 8 KB
  __shared__ __align__(16) unsigned short lB[128 * 32];   // 8 KB
  const int tid  = threadIdx.x;
  const int lane = tid & 63;
  const int wave = tid >> 6;
  const int bm = blockIdx.y * 128;
  const int bn = blockIdx.x * 128;            // chunk-local (global when jBase==0)
  const int wm = (wave >> 1) * 64;
  const int wn = (wave & 1) * 64;

  f32x4 acc[4][4];
#pragma unroll
  for (int mi = 0; mi < 4; ++mi)
#pragma unroll
    for (int ni = 0; ni < 4; ++ni)
      acc[mi][ni] = (f32x4)0.0f;

  const unsigned short* Ab = A + (size_t)bm * DDIM;
  const unsigned short* Bb = B + (size_t)(jBase + bn) * DDIM;
  const int stRow  = lane >> 2;          // 16 rows per 1024B wave region
  const int stColH = (lane & 3) * 8;     // ushort offset in 64B row

  for (int kt = 0; kt < DDIM / 32; ++kt) {
#pragma unroll
    for (int p = 0; p < 2; ++p) {
      const int off = (p * 4 + wave) * 1024;    // byte offset into 8KB tile
      const int r0  = off >> 6;
      gload_lds16(Ab + (size_t)(r0 + stRow) * DDIM + kt * 32 + stColH, (char*)lA + off);
      gload_lds16(Bb + (size_t)(r0 + stRow) * DDIM + kt * 32 + stColH, (char*)lB + off);
    }
    __syncthreads();

    bf16x8 af[4], bfr[4];
#pragma unroll
    for (int mi = 0; mi < 4; ++mi) {
      const int r = wm + mi * 16 + (lane & 15);
      af[mi] = *(const bf16x8*)((const char*)lA + r * 64 + (lane >> 4) * 16);
    }
#pragma unroll
    for (int ni = 0; ni < 4; ++ni) {
      const int r = wn + ni * 16 + (lane & 15);
      bfr[ni] = *(const bf16x8*)((const char*)lB + r * 64 + (lane >> 4) * 16);
    }
#pragma unroll
    for (int mi = 0; mi < 4; ++mi)
#pragma unroll
      for (int ni = 0; ni < 4; ++ni)
        acc[mi][ni] = __builtin_amdgcn_mfma_f32_16x16x32_bf16(af[mi], bfr[ni], acc[mi][ni], 0, 0, 0);
    __syncthreads();
  }

  // C/D layout (m89-verified): col = lane&15, row = (lane>>4)*4 + reg
  if (STORE_SQ == 0) {
#pragma unroll
    for (int mi = 0; mi < 4; ++mi) {
#pragma unroll
      for (int j = 0; j < 4; ++j) {
        const int i = bm + wm + mi * 16 + ((lane >> 4) << 2) + j;
        const float av = a2[i];
        float mn = __builtin_inff();
#pragma unroll
        for (int ni = 0; ni < 4; ++ni) {
          const int jj = bn + wn + ni * 16 + (lane & 15);
          const float sq = av + b2[jj] - 2.0f * acc[mi][ni][j];
          mn = fminf(mn, sq);
        }
#pragma unroll
        for (int s = 1; s < 16; s <<= 1) mn = fminf(mn, __shfl_xor(mn, s));
        if ((lane & 15) == 0) atomicMin(&rowMin[i], __float_as_uint(fmaxf(mn, 0.0f)));
      }
    }
  } else {
#pragma unroll
    for (int mi = 0; mi < 4; ++mi) {
#pragma unroll
      for (int j = 0; j < 4; ++j) {
        const int i = bm + wm + mi * 16 + ((lane >> 4) << 2) + j;
        const float av = a2[i];
#pragma unroll
        for (int ni = 0; ni < 4; ++ni) {
          const int jj = bn + wn + ni * 16 + (lane & 15);
          sqbuf[(size_t)i * chunkCols + jj] = av + b2[jBase + jj] - 2.0f * acc[mi][ni][j];
        }
      }
    }
  }
}

// ---------------- flag: any row with clamped min-sq < MARGIN^2 ? ------------
__global__ __launch_bounds__(256) void flag_kernel(const unsigned int* __restrict__ rowMin,
                                                   int* __restrict__ flag)
{
  const int i = blockIdx.x * 256 + threadIdx.x;
  if (i < NROWS && rowMin[i] < 0x40800000u /* bits(4.0f) */) atomicExch(flag, 1);
}

// ---------------- exact top-30 per row (fallback; flag-gated) ---------------
// One wave per row. Chunk values live in registers (VPL per lane). Running
// top-30 carried via tv/ti. Extraction = 30x lexicographic (val, col) argmin
// with static-index exclusion; matches lax.top_k stable tie-breaking.
template<int VPL>
__global__ __launch_bounds__(64) void select_kernel(
    const float* __restrict__ sqbuf, const int* __restrict__ flag,
    float* __restrict__ tv, int* __restrict__ ti, int jBase, int isFirst)
{
  if (*flag == 0) return;
  const int row = blockIdx.x, lane = threadIdx.x;
  const int CH = VPL * 64;
  float v[VPL];
#pragma unroll
  for (int q = 0; q < VPL; ++q)
    v[q] = sqbuf[(size_t)row * CH + q * 64 + lane];
  float cv; int ci;
  if (isFirst) { cv = __builtin_inff(); ci = 0x7fffffff; }
  else {
    cv = (lane < NQ) ? tv[row * 32 + lane] : __builtin_inff();
    ci = (lane < NQ) ? ti[row * 32 + lane] : 0x7fffffff;
  }
  for (int k = 0; k < NQ; ++k) {
    float mv = cv; int mi_ = ci;
#pragma unroll
    for (int q = 0; q < VPL; ++q) {
      const int col = jBase + q * 64 + lane;
      const bool b = (v[q] < mv) || (v[q] == mv && col < mi_);
      mv  = b ? v[q] : mv;
      mi_ = b ? col  : mi_;
    }
#pragma unroll
    for (int s = 1; s < 64; s <<= 1) {
      const float ov = __shfl_xor(mv, s);
      const int   oi = __shfl_xor(mi_, s);
      const bool b = (ov < mv) || (ov == mv && oi < mi_);
      mv  = b ? ov : mv;
      mi_ = b ? oi : mi_;
    }
    // exclude extracted element (carry slot or this chunk, static indices only)
    if (mi_ == ci) cv = __builtin_inff();
    else if (mi_ >= jBase) {
      const int rel = mi_ - jBase;
      if ((rel & 63) == lane) {
        const int lq = rel >> 6;
#pragma unroll
        for (int q = 0; q < VPL; ++q) if (q == lq) v[q] = __builtin_inff();
      }
    }
    if (lane == 0) { tv[row * 32 + k] = mv; ti[row * 32 + k] = mi_; }
  }
}

// ---------------- final reduction ------------------------------------------
__global__ __launch_bounds__(256) void final_kernel(
    const float* __restrict__ posr, const float* __restrict__ tv,
    const int* __restrict__ ti, const int* __restrict__ rn,
    const int* __restrict__ flag, float* __restrict__ out)
{
  const int t = threadIdx.x;
  const int useNeg = (*flag != 0);
  double ps = 0.0, ns = 0.0;
  for (int r = t; r < NROWS; r += 256) {
    ps += (double)posr[r];
    if (useNeg) {
      int k = rn[r];
      const int sel = ti[r * 32 + k];
      if (sel == r) k = (k + 1) % NQ;
      const float d = sqrtf(fmaxf(tv[r * 32 + k], 0.0f));
      ns += (double)fmaxf(MARGINF - d, 0.0f);
    }
  }
  __shared__ double sp[256], sn[256];
  sp[t] = ps; sn[t] = ns;
  __syncthreads();
  for (int s = 128; s > 0; s >>= 1) {
    if (t < s) { sp[t] += sp[t + s]; sn[t] += sn[t + s]; }
    __syncthreads();
  }
  if (t == 0) out[0] = (float)(sp[0] / NROWS + sn[0] / NROWS);
}

extern "C" void kernel_launch(void* const* d_in, const int* in_sizes, int n_in,
                              void* d_out, int out_size, void* d_ws, size_t ws_size,
                              hipStream_t stream) {
  (void)in_sizes; (void)n_in; (void)out_size;
  const float* o1 = (const float*)d_in[0];
  const float* o2 = (const float*)d_in[1];
  const int*   rn = (const int*)d_in[2];
  float* out = (float*)d_out;

  char* ws = (char*)d_ws;
  size_t off = 0;
  auto alloc = [&](size_t b) { void* p = ws + off; off += (b + 255) & ~(size_t)255; return p; };
  unsigned short* o1b = (unsigned short*)alloc((size_t)NROWS * DDIM * 2);  // 16 MB
  unsigned short* o2b = (unsigned short*)alloc((size_t)NROWS * DDIM * 2);  // 16 MB
  float* a2   = (float*)alloc((size_t)NROWS * 4);
  float* b2   = (float*)alloc((size_t)NROWS * 4);
  float* posr = (float*)alloc((size_t)NROWS * 4);
  unsigned int* rowMin = (unsigned int*)alloc((size_t)NROWS * 4);
  int*   flag = (int*)alloc(256);
  float* tv   = (float*)alloc((size_t)NROWS * 32 * 4);   // 1 MB
  int*   ti   = (int*)alloc((size_t)NROWS * 32 * 4);     // 1 MB
  const size_t remain = ws_size > off ? ws_size - off : 0;
  int chunk;
  if      (remain >= (size_t)NROWS * 8192 * 4) chunk = 8192;
  else if (remain >= (size_t)NROWS * 2048 * 4) chunk = 2048;
  else if (remain >= (size_t)NROWS * 512 * 4)  chunk = 512;
  else                                         chunk = 128;  // fallback never touched when flag==0
  float* sqbuf = (float*)(ws + off);

  prep_kernel<<<NROWS, 256, 0, stream>>>(o1, o2, o1b, o2b, a2, b2, posr, rowMin, flag);
  gemm_kernel<0><<<dim3(64, 64), 256, 0, stream>>>(o1b, o2b, a2, b2, rowMin, flag, nullptr, 0, 0);
  flag_kernel<<<dim3(NROWS / 256), 256, 0, stream>>>(rowMin, flag);
  const int nch = NROWS / chunk;
  for (int c = 0; c < nch; ++c) {
    gemm_kernel<1><<<dim3(chunk / 128, 64), 256, 0, stream>>>(o1b, o2b, a2, b2, rowMin, flag,
                                                              sqbuf, c * chunk, chunk);
    const int first = (c == 0);
    if      (chunk == 8192) select_kernel<128><<<NROWS, 64, 0, stream>>>(sqbuf, flag, tv, ti, c * chunk, first);
    else if (chunk == 2048) select_kernel<32><<<NROWS, 64, 0, stream>>>(sqbuf, flag, tv, ti, c * chunk, first);
    else if (chunk == 512)  select_kernel<8><<<NROWS, 64, 0, stream>>>(sqbuf, flag, tv, ti, c * chunk, first);
    else                    select_kernel<2><<<NROWS, 64, 0, stream>>>(sqbuf, flag, tv, ti, c * chunk, first);
  }
  final_kernel<<<1, 256, 0, stream>>>(posr, tv, ti, rn, flag, out);
}

// Round 2
// 221.667 us; speedup vs baseline: 1.1261x; 1.1261x over previous
//
#include <hip/hip_runtime.h>
#include <hip/hip_bf16.h>
#include <stdint.h>

#define NROWS 8192
#define DDIM  1024
#define NQ    30
#define MARGINF 2.0f

typedef __attribute__((ext_vector_type(8))) short bf16x8;   // 8 bf16 (4 VGPRs)
typedef __attribute__((ext_vector_type(4))) float f32x4;    // MFMA accum

static __device__ __forceinline__ unsigned short f2bf(float f) {
  union { float f; unsigned u; } c; c.f = f;
  return (unsigned short)((c.u + 0x7fffu + ((c.u >> 16) & 1u)) >> 16);  // RNE
}

static __device__ __forceinline__ void gload_lds16(const void* g, void* l) {
  __builtin_amdgcn_global_load_lds(
      (const __attribute__((address_space(1))) void*)g,
      (__attribute__((address_space(3))) void*)l, 16, 0, 0);
}

// ---------------- prep: bf16 cast + row norms + pos term + rowMin init -------
__global__ __launch_bounds__(256) void prep_kernel(
    const float* __restrict__ o1, const float* __restrict__ o2,
    unsigned short* __restrict__ o1b, unsigned short* __restrict__ o2b,
    float* __restrict__ a2, float* __restrict__ b2, float* __restrict__ posr,
    unsigned int* __restrict__ rowMin, int* __restrict__ flag)
{
  const int row = blockIdx.x;
  const int t = threadIdx.x;
  const float4* p1 = (const float4*)(o1 + (size_t)row * DDIM);
  const float4* p2 = (const float4*)(o2 + (size_t)row * DDIM);
  float4 x1 = p1[t];
  float4 x2 = p2[t];
  float s1, s2, sp;
  {
    float a0 = x1.x, a1 = x1.y, aa2 = x1.z, a3 = x1.w;
    float b0 = x2.x, b1 = x2.y, bb2 = x2.z, b3 = x2.w;
    s1 = a0*a0 + a1*a1 + aa2*aa2 + a3*a3;
    s2 = b0*b0 + b1*b1 + bb2*bb2 + b3*b3;
    float d0 = b0-a0, d1 = b1-a1, d2 = bb2-aa2, d3 = b3-a3;
    sp = d0*d0 + d1*d1 + d2*d2 + d3*d3;
    ushort4 v1 = make_ushort4(f2bf(a0), f2bf(a1), f2bf(aa2), f2bf(a3));
    ushort4 v2 = make_ushort4(f2bf(b0), f2bf(b1), f2bf(bb2), f2bf(b3));
    *(ushort4*)(o1b + (size_t)row * DDIM + t * 4) = v1;
    *(ushort4*)(o2b + (size_t)row * DDIM + t * 4) = v2;
  }
  for (int s = 1; s < 64; s <<= 1) {
    s1 += __shfl_xor(s1, s);
    s2 += __shfl_xor(s2, s);
    sp += __shfl_xor(sp, s);
  }
  __shared__ float r1[4], r2[4], rp[4];
  const int wv = t >> 6;
  if ((t & 63) == 0) { r1[wv] = s1; r2[wv] = s2; rp[wv] = sp; }
  __syncthreads();
  if (t == 0) {
    a2[row]   = r1[0] + r1[1] + r1[2] + r1[3];
    b2[row]   = r2[0] + r2[1] + r2[2] + r2[3];
    posr[row] = rp[0] + rp[1] + rp[2] + rp[3];
    rowMin[row] = 0x7F800000u;           // +inf bits
    if (row == 0) *flag = 0;
  }
}

// ============================================================================
// 256x256-tile, BK=64, 8-wave (2Mx4N), 8-phase counted-vmcnt GEMM -> rowMin.
// LDS: 2 bufs (even/odd K-tile) x {A,B} x 256x64 bf16 = 128 KB (dynamic).
// Swizzle: 16B slot p = s ^ (row&7); linear gload_lds dest + pre-swizzled
// global source + swizzled ds_read (rule #21 both-sides involution).
// Schedule (per iter = K-tiles 2i [buf0] and 2i+1 [buf1]); 2 chunks staged
// per phase; vmcnt(4) at P4/P8 covers every read (paper-verified windows).
// ============================================================================
#define STG(b,m,c,kt) gload_lds16((((m)?Bg:Ag) + (size_t)(c)*64*1024 + (size_t)(kt)*64), \
                                  lds + ((b)*2+(m))*16384 + (c)*4096 + tid*8)

#define LDA_(dst,b,mibase) \
  _Pragma("unroll") for (int mi_=0; mi_<4; ++mi_) \
  _Pragma("unroll") for (int kk_=0; kk_<2; ++kk_) \
    dst[mi_][kk_] = *(const bf16x8*)(lds + (b)*32768 + aoff + ((mibase)+mi_)*1024 + (kk_?sw1:sw0));

#define LDB_(dst,b,nibase) \
  _Pragma("unroll") for (int ni_=0; ni_<2; ++ni_) \
  _Pragma("unroll") for (int kk_=0; kk_<2; ++kk_) \
    dst[ni_][kk_] = *(const bf16x8*)(lds + (b)*32768 + boff + ((nibase)+ni_)*1024 + (kk_?sw1:sw0));

#define MMQ(AF,BF,MOFF,NOFF) do { \
  __builtin_amdgcn_s_setprio(1); \
  _Pragma("unroll") for (int mi_=0; mi_<4; ++mi_) \
  _Pragma("unroll") for (int ni_=0; ni_<2; ++ni_) \
  _Pragma("unroll") for (int kk_=0; kk_<2; ++kk_) \
    acc[mi_+(MOFF)][ni_+(NOFF)] = __builtin_amdgcn_mfma_f32_16x16x32_bf16( \
        AF[mi_][kk_], BF[ni_][kk_], acc[mi_+(MOFF)][ni_+(NOFF)], 0, 0, 0); \
  __builtin_amdgcn_s_setprio(0); \
} while (0)

#define BAR() __builtin_amdgcn_s_barrier()
#define VMC4() asm volatile("s_waitcnt vmcnt(4)" ::: "memory")

__global__ __launch_bounds__(512, 2) void gemm256_kernel(
    const unsigned short* __restrict__ A, const unsigned short* __restrict__ B,
    const float* __restrict__ a2, const float* __restrict__ b2,
    unsigned int* __restrict__ rowMin)
{
  extern __shared__ __align__(16) unsigned short lds[];
  const int tid  = threadIdx.x;
  const int lane = tid & 63;
  const int wave = tid >> 6;
  const int wr = wave >> 2;      // 2 M-wave rows
  const int wc = wave & 3;       // 4 N-wave cols
  const int bm = blockIdx.y * 256;
  const int bn = blockIdx.x * 256;

  // ---- staging constants (per-thread, kt-independent) ----
  const int srow  = tid >> 3;                  // 0..63 row within 64-row chunk
  const int sslot = (tid & 7) ^ (srow & 7);    // logical 16B slot (involution)
  const unsigned short* Ag = A + (size_t)(bm + srow) * 1024 + sslot * 8;
  const unsigned short* Bg = B + (size_t)(bn + srow) * 1024 + sslot * 8;

  // ---- read-side constants ----
  const int rlane = lane & 15;
  const int hi    = lane >> 4;
  const int rx7   = rlane & 7;
  const int sw0   = ((0 * 4 + hi) ^ rx7) * 8;   // kk=0 swizzled slot (ushorts)
  const int sw1   = ((1 * 4 + hi) ^ rx7) * 8;   // kk=1
  const int aoff  = (wr * 128 + rlane) * 64;            // A tile row base
  const int boff  = 16384 + (wc * 64 + rlane) * 64;     // B tile row base

  f32x4 acc[8][4];
#pragma unroll
  for (int i = 0; i < 8; ++i)
#pragma unroll
    for (int j = 0; j < 4; ++j) acc[i][j] = (f32x4)0.0f;

  // ---- prologue: buf0 full T0 (A+B), buf1 A of T1; newest 4 may stay in flight
#pragma unroll
  for (int c = 0; c < 4; ++c) STG(0, 0, c, 0);
#pragma unroll
  for (int c = 0; c < 4; ++c) STG(0, 1, c, 0);
#pragma unroll
  for (int c = 0; c < 4; ++c) STG(1, 0, c, 1);
  VMC4();
  BAR();

#pragma unroll 1
  for (int it = 0; it < 8; ++it) {
    const int k1 = 2 * it + 1;
    int k2 = 2 * it + 2; if (k2 > 15) k2 = 15;   // tail: restage valid data, never read
    int k3 = 2 * it + 3; if (k3 > 15) k3 = 15;
    bf16x8 alo[4][2], ahi[4][2], blo[2][2], bhi[2][2];
    // P1: read buf0 A-lo + B-lo; stage buf1.B01 (T_2i+1, read P5 this iter)
    LDA_(alo, 0, 0); LDB_(blo, 0, 0);
    STG(1, 1, 0, k1); STG(1, 1, 1, k1);
    BAR(); MMQ(alo, blo, 0, 0); BAR();
    // P2: read buf0 B-hi; stage buf1.B23
    LDB_(bhi, 0, 2);
    STG(1, 1, 2, k1); STG(1, 1, 3, k1);
    BAR(); MMQ(alo, bhi, 0, 2); BAR();
    // P3: read buf0 A-hi; stage buf0.A02 (T_2i+2; A-lo chunks freed at P1)
    LDA_(ahi, 0, 4);
    STG(0, 0, 0, k2); STG(0, 0, 2, k2);
    BAR(); MMQ(ahi, blo, 4, 0); BAR();
    // P4: stage buf0.A13 (freed P3); counted wait -> all through P2 complete
    STG(0, 0, 1, k2); STG(0, 0, 3, k2);
    VMC4();
    BAR(); MMQ(ahi, bhi, 4, 2); BAR();
    // P5: read buf1 A-lo + B-lo; stage buf0.B01 (B chunks freed at P2)
    LDA_(alo, 1, 0); LDB_(blo, 1, 0);
    STG(0, 1, 0, k2); STG(0, 1, 1, k2);
    BAR(); MMQ(alo, blo, 0, 0); BAR();
    // P6: read buf1 B-hi; stage buf0.B23
    LDB_(bhi, 1, 2);
    STG(0, 1, 2, k2); STG(0, 1, 3, k2);
    BAR(); MMQ(alo, bhi, 0, 2); BAR();
    // P7: read buf1 A-hi; stage buf1.A02 (T_2i+3; freed P5)
    LDA_(ahi, 1, 4);
    STG(1, 0, 0, k3); STG(1, 0, 2, k3);
    BAR(); MMQ(ahi, blo, 4, 0); BAR();
    // P8: stage buf1.A13 (freed P7); counted wait -> all through P6 complete
    STG(1, 0, 1, k3); STG(1, 0, 3, k3);
    VMC4();
    BAR(); MMQ(ahi, bhi, 4, 2); BAR();
  }

  // ---- epilogue: per-row min of sq over this wave's 64-col span -> atomicMin
  float b2v[4];
#pragma unroll
  for (int ni = 0; ni < 4; ++ni) b2v[ni] = b2[bn + wc * 64 + ni * 16 + rlane];
#pragma unroll
  for (int mi = 0; mi < 8; ++mi) {
#pragma unroll
    for (int j = 0; j < 4; ++j) {
      const int row = bm + wr * 128 + mi * 16 + (hi << 2) + j;   // C/D: col=lane&15, row=(lane>>4)*4+reg
      const float av = a2[row];
      float mn = av + b2v[0] - 2.0f * acc[mi][0][j];
#pragma unroll
      for (int ni = 1; ni < 4; ++ni) mn = fminf(mn, av + b2v[ni] - 2.0f * acc[mi][ni][j]);
#pragma unroll
      for (int s = 1; s < 16; s <<= 1) mn = fminf(mn, __shfl_xor(mn, s));
      if (rlane == 0) atomicMin(&rowMin[row], __float_as_uint(fmaxf(mn, 0.0f)));
    }
  }
}

// ---------------- 128^2-tile GEMM (fallback path + flag-gated sq store) ----
template<int STORE_SQ>
__global__ __launch_bounds__(256) void gemm_kernel(
    const unsigned short* __restrict__ A, const unsigned short* __restrict__ B,
    const float* __restrict__ a2, const float* __restrict__ b2,
    unsigned int* __restrict__ rowMin, const int* __restrict__ flag,
    float* __restrict__ sqbuf, int jBase, int chunkCols)
{
  if (STORE_SQ) { if (*flag == 0) return; }   // fallback gate (never taken on benign data)
  __shared__ __align__(16) unsigned short lA[128 * 32];
  __shared__ __align__(16) unsigned short lB[128 * 32];
  const int tid  = threadIdx.x;
  const int lane = tid & 63;
  const int wave = tid >> 6;
  const int bm = blockIdx.y * 128;
  const int bn = blockIdx.x * 128;
  const int wm = (wave >> 1) * 64;
  const int wn = (wave & 1) * 64;

  f32x4 acc[4][4];
#pragma unroll
  for (int mi = 0; mi < 4; ++mi)
#pragma unroll
    for (int ni = 0; ni < 4; ++ni)
      acc[mi][ni] = (f32x4)0.0f;

  const unsigned short* Ab = A + (size_t)bm * DDIM;
  const unsigned short* Bb = B + (size_t)(jBase + bn) * DDIM;
  const int stRow  = lane >> 2;
  const int stColH = (lane & 3) * 8;

  for (int kt = 0; kt < DDIM / 32; ++kt) {
#pragma unroll
    for (int p = 0; p < 2; ++p) {
      const int off = (p * 4 + wave) * 1024;
      const int r0  = off >> 6;
      gload_lds16(Ab + (size_t)(r0 + stRow) * DDIM + kt * 32 + stColH, (char*)lA + off);
      gload_lds16(Bb + (size_t)(r0 + stRow) * DDIM + kt * 32 + stColH, (char*)lB + off);
    }
    __syncthreads();

    bf16x8 af[4], bfr[4];
#pragma unroll
    for (int mi = 0; mi < 4; ++mi) {
      const int r = wm + mi * 16 + (lane & 15);
      af[mi] = *(const bf16x8*)((const char*)lA + r * 64 + (lane >> 4) * 16);
    }
#pragma unroll
    for (int ni = 0; ni < 4; ++ni) {
      const int r = wn + ni * 16 + (lane & 15);
      bfr[ni] = *(const bf16x8*)((const char*)lB + r * 64 + (lane >> 4) * 16);
    }
#pragma unroll
    for (int mi = 0; mi < 4; ++mi)
#pragma unroll
      for (int ni = 0; ni < 4; ++ni)
        acc[mi][ni] = __builtin_amdgcn_mfma_f32_16x16x32_bf16(af[mi], bfr[ni], acc[mi][ni], 0, 0, 0);
    __syncthreads();
  }

  if (STORE_SQ == 0) {
#pragma unroll
    for (int mi = 0; mi < 4; ++mi) {
#pragma unroll
      for (int j = 0; j < 4; ++j) {
        const int i = bm + wm + mi * 16 + ((lane >> 4) << 2) + j;
        const float av = a2[i];
        float mn = __builtin_inff();
#pragma unroll
        for (int ni = 0; ni < 4; ++ni) {
          const int jj = bn + wn + ni * 16 + (lane & 15);
          const float sq = av + b2[jj] - 2.0f * acc[mi][ni][j];
          mn = fminf(mn, sq);
        }
#pragma unroll
        for (int s = 1; s < 16; s <<= 1) mn = fminf(mn, __shfl_xor(mn, s));
        if ((lane & 15) == 0) atomicMin(&rowMin[i], __float_as_uint(fmaxf(mn, 0.0f)));
      }
    }
  } else {
#pragma unroll
    for (int mi = 0; mi < 4; ++mi) {
#pragma unroll
      for (int j = 0; j < 4; ++j) {
        const int i = bm + wm + mi * 16 + ((lane >> 4) << 2) + j;
        const float av = a2[i];
#pragma unroll
        for (int ni = 0; ni < 4; ++ni) {
          const int jj = bn + wn + ni * 16 + (lane & 15);
          sqbuf[(size_t)i * chunkCols + jj] = av + b2[jBase + jj] - 2.0f * acc[mi][ni][j];
        }
      }
    }
  }
}

// ---------------- flag: any row with clamped min-sq < MARGIN^2 ? ------------
__global__ __launch_bounds__(256) void flag_kernel(const unsigned int* __restrict__ rowMin,
                                                   int* __restrict__ flag)
{
  const int i = blockIdx.x * 256 + threadIdx.x;
  if (i < NROWS && rowMin[i] < 0x40800000u /* bits(4.0f) */) atomicExch(flag, 1);
}

// ---------------- exact top-30 per row (fallback; flag-gated) ---------------
template<int VPL>
__global__ __launch_bounds__(64) void select_kernel(
    const float* __restrict__ sqbuf, const int* __restrict__ flag,
    float* __restrict__ tv, int* __restrict__ ti, int jBase, int isFirst)
{
  if (*flag == 0) return;
  const int row = blockIdx.x, lane = threadIdx.x;
  const int CH = VPL * 64;
  float v[VPL];
#pragma unroll
  for (int q = 0; q < VPL; ++q)
    v[q] = sqbuf[(size_t)row * CH + q * 64 + lane];
  float cv; int ci;
  if (isFirst) { cv = __builtin_inff(); ci = 0x7fffffff; }
  else {
    cv = (lane < NQ) ? tv[row * 32 + lane] : __builtin_inff();
    ci = (lane < NQ) ? ti[row * 32 + lane] : 0x7fffffff;
  }
  for (int k = 0; k < NQ; ++k) {
    float mv = cv; int mi_ = ci;
#pragma unroll
    for (int q = 0; q < VPL; ++q) {
      const int col = jBase + q * 64 + lane;
      const bool b = (v[q] < mv) || (v[q] == mv && col < mi_);
      mv  = b ? v[q] : mv;
      mi_ = b ? col  : mi_;
    }
#pragma unroll
    for (int s = 1; s < 64; s <<= 1) {
      const float ov = __shfl_xor(mv, s);
      const int   oi = __shfl_xor(mi_, s);
      const bool b = (ov < mv) || (ov == mv && oi < mi_);
      mv  = b ? ov : mv;
      mi_ = b ? oi : mi_;
    }
    if (mi_ == ci) cv = __builtin_inff();
    else if (mi_ >= jBase) {
      const int rel = mi_ - jBase;
      if ((rel & 63) == lane) {
        const int lq = rel >> 6;
#pragma unroll
        for (int q = 0; q < VPL; ++q) if (q == lq) v[q] = __builtin_inff();
      }
    }
    if (lane == 0) { tv[row * 32 + k] = mv; ti[row * 32 + k] = mi_; }
  }
}

// ---------------- final reduction ------------------------------------------
__global__ __launch_bounds__(256) void final_kernel(
    const float* __restrict__ posr, const float* __restrict__ tv,
    const int* __restrict__ ti, const int* __restrict__ rn,
    const int* __restrict__ flag, float* __restrict__ out)
{
  const int t = threadIdx.x;
  const int useNeg = (*flag != 0);
  double ps = 0.0, ns = 0.0;
  for (int r = t; r < NROWS; r += 256) {
    ps += (double)posr[r];
    if (useNeg) {
      int k = rn[r];
      const int sel = ti[r * 32 + k];
      if (sel == r) k = (k + 1) % NQ;
      const float d = sqrtf(fmaxf(tv[r * 32 + k], 0.0f));
      ns += (double)fmaxf(MARGINF - d, 0.0f);
    }
  }
  __shared__ double sp[256], sn[256];
  sp[t] = ps; sn[t] = ns;
  __syncthreads();
  for (int s = 128; s > 0; s >>= 1) {
    if (t < s) { sp[t] += sp[t + s]; sn[t] += sn[t + s]; }
    __syncthreads();
  }
  if (t == 0) out[0] = (float)(sp[0] / NROWS + sn[0] / NROWS);
}

extern "C" void kernel_launch(void* const* d_in, const int* in_sizes, int n_in,
                              void* d_out, int out_size, void* d_ws, size_t ws_size,
                              hipStream_t stream) {
  (void)in_sizes; (void)n_in; (void)out_size;
  const float* o1 = (const float*)d_in[0];
  const float* o2 = (const float*)d_in[1];
  const int*   rn = (const int*)d_in[2];
  float* out = (float*)d_out;

  char* ws = (char*)d_ws;
  size_t off = 0;
  auto alloc = [&](size_t b) { void* p = ws + off; off += (b + 255) & ~(size_t)255; return p; };
  unsigned short* o1b = (unsigned short*)alloc((size_t)NROWS * DDIM * 2);  // 16 MB
  unsigned short* o2b = (unsigned short*)alloc((size_t)NROWS * DDIM * 2);  // 16 MB
  float* a2   = (float*)alloc((size_t)NROWS * 4);
  float* b2   = (float*)alloc((size_t)NROWS * 4);
  float* posr = (float*)alloc((size_t)NROWS * 4);
  unsigned int* rowMin = (unsigned int*)alloc((size_t)NROWS * 4);
  int*   flag = (int*)alloc(256);
  float* tv   = (float*)alloc((size_t)NROWS * 32 * 4);
  int*   ti   = (int*)alloc((size_t)NROWS * 32 * 4);
  const size_t remain = ws_size > off ? ws_size - off : 0;
  int chunk;
  if      (remain >= (size_t)NROWS * 8192 * 4) chunk = 8192;
  else if (remain >= (size_t)NROWS * 2048 * 4) chunk = 2048;
  else if (remain >= (size_t)NROWS * 512 * 4)  chunk = 512;
  else                                         chunk = 128;
  float* sqbuf = (float*)(ws + off);

  prep_kernel<<<NROWS, 256, 0, stream>>>(o1, o2, o1b, o2b, a2, b2, posr, rowMin, flag);

  // 256^2 8-phase kernel needs 128 KB dynamic LDS (opt-in). Fall back to the
  // validated 128^2 kernel if the attribute can't be set.
  hipError_t attrOk = hipFuncSetAttribute(
      reinterpret_cast<const void*>(gemm256_kernel),
      hipFuncAttributeMaxDynamicSharedMemorySize, 131072);
  if (attrOk == hipSuccess) {
    gemm256_kernel<<<dim3(NROWS / 256, NROWS / 256), 512, 131072, stream>>>(
        o1b, o2b, a2, b2, rowMin);
  } else {
    gemm_kernel<0><<<dim3(64, 64), 256, 0, stream>>>(o1b, o2b, a2, b2, rowMin, flag,
                                                     nullptr, 0, 0);
  }

  flag_kernel<<<dim3(NROWS / 256), 256, 0, stream>>>(rowMin, flag);
  const int nch = NROWS / chunk;
  for (int c = 0; c < nch; ++c) {
    gemm_kernel<1><<<dim3(chunk / 128, 64), 256, 0, stream>>>(o1b, o2b, a2, b2, rowMin, flag,
                                                              sqbuf, c * chunk, chunk);
    const int first = (c == 0);
    if      (chunk == 8192) select_kernel<128><<<NROWS, 64, 0, stream>>>(sqbuf, flag, tv, ti, c * chunk, first);
    else if (chunk == 2048) select_kernel<32><<<NROWS, 64, 0, stream>>>(sqbuf, flag, tv, ti, c * chunk, first);
    else if (chunk == 512)  select_kernel<8><<<NROWS, 64, 0, stream>>>(sqbuf, flag, tv, ti, c * chunk, first);
    else                    select_kernel<2><<<NROWS, 64, 0, stream>>>(sqbuf, flag, tv, ti, c * chunk, first);
  }
  final_kernel<<<1, 256, 0, stream>>>(posr, tv, ti, rn, flag, out);
}